// Round 9
// baseline (40.977 us; speedup 1.0000x reference)
//
#include <hip/hip_runtime.h>

#define F_ALPHA 0.25f
#define F_EPS   1e-8f
#define NB 4          // preds per block
#define TMAX 1600
#define Q4   (TMAX/4) // 400 target-quads

// R5 skeleton + wide stores.
// Phase A: stage targets into residue-SoA LDS: sTbS[(t&3)*Q4 + t/4].
// Phase 1: transposed prescaled focal table fclsT[class] = float4 over NB preds.
// Phase 2: thread owns 4 consecutive targets (quad q): conflict-free b128 LDS
//          reads, 16 pair costs, 4 float4 stores (one per pred row).
__global__ void __launch_bounds__(256)
fused_cost_kernel(const float* __restrict__ logits,      // [N, C]
                  const float4* __restrict__ pred_boxes, // [N]
                  const float4* __restrict__ tgt_boxes,  // [T]
                  const int* __restrict__ tgt_ids,       // [T]
                  float* __restrict__ out,               // [N, T]
                  int N, int C, int T) {
    __shared__ float4 sTbS[TMAX];         // 25.6 KB, residue-SoA target boxes
    __shared__ int    sIdS[TMAX];         // 6.4 KB, residue-SoA ids
    __shared__ float4 fclsT[96];          // [class] -> NB prescaled costs

    const int n0  = blockIdx.x * NB;
    const int tid = threadIdx.x;

    // ---- phase A: coalesced load, swizzled store ----
    for (int t = tid; t < TMAX; t += 256) {
        int s = (t & 3) * Q4 + (t >> 2);
        sTbS[s] = tgt_boxes[t];
        sIdS[s] = tgt_ids[t];
    }

    // ---- phase 1: wave w computes pred (n0+w)'s focal row, transposed ----
    {
        const int w = tid >> 6, l = tid & 63;
        const float* lrow = logits + (size_t)(n0 + w) * C;
        for (int c = l; c < C; c += 64) {
            float x = lrow[c];
            float p = 1.0f / (1.0f + expf(-x));
            float om = 1.0f - p;
            float pos = F_ALPHA * om * om * (-logf(p + F_EPS));
            float neg = (1.0f - F_ALPHA) * p * p * (-logf(om + F_EPS));
            ((float*)fclsT)[c * NB + w] = 2.0f * (pos - neg) + 2.0f;
        }
    }

    // pred-side params (block-uniform)
    float pcx[NB], pcy[NB], pw_[NB], ph_[NB];
    float px1[NB], py1[NB], px2[NB], py2[NB], parea[NB];
    float4* op[NB];
#pragma unroll
    for (int i = 0; i < NB; ++i) {
        const int n = n0 + i;                       // N % NB == 0
        float4 pb = pred_boxes[n];
        pcx[i] = pb.x; pcy[i] = pb.y; pw_[i] = pb.z; ph_[i] = pb.w;
        px1[i] = pb.x - 0.5f * pb.z;  py1[i] = pb.y - 0.5f * pb.w;
        px2[i] = pb.x + 0.5f * pb.z;  py2[i] = pb.y + 0.5f * pb.w;
        parea[i] = pb.z * pb.w;
        op[i] = (float4*)(out + (size_t)n * T);
    }
    __syncthreads();

    // ---- phase 2: quads q = tid, tid+256 ----
    for (int q = tid; q < Q4; q += 256) {
        float4 tb[4]; float4 cls[4];
        float tx1[4], ty1[4], tx2[4], ty2[4], tarea[4];
#pragma unroll
        for (int j = 0; j < 4; ++j) {
            tb[j] = sTbS[j * Q4 + q];               // b128, unit lane stride
            cls[j] = fclsT[sIdS[j * Q4 + q]];       // b32 + random b128
            tx1[j] = tb[j].x - 0.5f * tb[j].z;  ty1[j] = tb[j].y - 0.5f * tb[j].w;
            tx2[j] = tb[j].x + 0.5f * tb[j].z;  ty2[j] = tb[j].y + 0.5f * tb[j].w;
            tarea[j] = tb[j].z * tb[j].w;
        }
        const float clsv[4][4] = {
            {cls[0].x, cls[0].y, cls[0].z, cls[0].w},
            {cls[1].x, cls[1].y, cls[1].z, cls[1].w},
            {cls[2].x, cls[2].y, cls[2].z, cls[2].w},
            {cls[3].x, cls[3].y, cls[3].z, cls[3].w}};
#pragma unroll
        for (int i = 0; i < NB; ++i) {
            float res[4];
#pragma unroll
            for (int j = 0; j < 4; ++j) {
                float l1 = (fabsf(pcx[i] - tb[j].x) + fabsf(pcy[i] - tb[j].y))
                         + (fabsf(pw_[i] - tb[j].z) + fabsf(ph_[i] - tb[j].w));

                float ix1 = fmaxf(px1[i], tx1[j]), iy1 = fmaxf(py1[i], ty1[j]);
                float ix2 = fminf(px2[i], tx2[j]), iy2 = fminf(py2[i], ty2[j]);
                float iw = fmaxf(ix2 - ix1, 0.0f), ih = fmaxf(iy2 - iy1, 0.0f);
                float inter = iw * ih;
                float uni = parea[i] + tarea[j] - inter;

                float ex1 = fminf(px1[i], tx1[j]), ey1 = fminf(py1[i], ty1[j]);
                float ex2 = fmaxf(px2[i], tx2[j]), ey2 = fmaxf(py2[i], ty2[j]);
                float earea = (ex2 - ex1) * (ey2 - ey1);  // wh >= 0, [0,1) boxes

                float v = fmaf(5.0f, l1, clsv[j][i]);     // 5*l1 + 2*cls + 2
                v = fmaf(-2.0f, inter * __builtin_amdgcn_rcpf(uni), v);
                v = fmaf(-2.0f, uni * __builtin_amdgcn_rcpf(earea), v);
                res[j] = v;
            }
            op[i][q] = make_float4(res[0], res[1], res[2], res[3]); // 16B store
        }
    }
}

extern "C" void kernel_launch(void* const* d_in, const int* in_sizes, int n_in,
                              void* d_out, int out_size, void* d_ws, size_t ws_size,
                              hipStream_t stream) {
    const float* logits = (const float*)d_in[0];   // [bs, Q, C]
    const float* pboxes = (const float*)d_in[1];   // [bs, Q, 4]
    const float* tboxes = (const float*)d_in[2];   // [T, 4]
    const int*   tids   = (const int*)d_in[3];     // [T]

    int N = in_sizes[1] / 4;          // bs*Q = 14400
    int C = in_sizes[0] / N;          // 91
    int T = in_sizes[2] / 4;          // 1600

    int grid = N / NB;                // 3600
    fused_cost_kernel<<<grid, 256, 0, stream>>>(
        logits, (const float4*)pboxes, (const float4*)tboxes, tids,
        (float*)d_out, N, C, T);
}

// Round 10
// 34.406 us; speedup vs baseline: 1.1910x; 1.1910x over previous
//
#include <hip/hip_runtime.h>

#define F_ALPHA 0.25f
#define F_EPS   1e-8f
#define NB 4   // preds per block

// R5 structure + software-pipelined target loads:
// the NEXT iteration's global loads are issued BEFORE this iteration's stores,
// so the wave's s_waitcnt for load data never has to drain the younger stores
// (vmcnt is in-order: waiting for older ops leaves younger stores in flight).
__global__ void __launch_bounds__(256)
fused_cost_kernel(const float* __restrict__ logits,      // [N, C]
                  const float4* __restrict__ pred_boxes, // [N]
                  const float4* __restrict__ tgt_boxes,  // [T]
                  const int* __restrict__ tgt_ids,       // [T]
                  float* __restrict__ out,               // [N, T]
                  int N, int C, int T) {
    __shared__ float fcls[NB][96];                       // C <= 96
    const int n0  = blockIdx.x * NB;
    const int tid = threadIdx.x;

    // ---- phase 1: one wave per pred row ----
    {
        const int w = tid >> 6, l = tid & 63;
        const int n = min(n0 + w, N - 1);
        const float* lrow = logits + (size_t)n * C;
        for (int c = l; c < C; c += 64) {
            float x = lrow[c];
            float p = 1.0f / (1.0f + expf(-x));
            float om = 1.0f - p;
            float pos = F_ALPHA * om * om * (-logf(p + F_EPS));
            float neg = (1.0f - F_ALPHA) * p * p * (-logf(om + F_EPS));
            fcls[w][c] = 2.0f * (pos - neg) + 2.0f;      // prescaled 2*cls+2
        }
    }

    // pred-side params (block-uniform) + output row pointers
    float pcx[NB], pcy[NB], pw_[NB], ph_[NB];
    float px1[NB], py1[NB], px2[NB], py2[NB], parea[NB];
    float* op[NB];
#pragma unroll
    for (int i = 0; i < NB; ++i) {
        const int n = min(n0 + i, N - 1);                // no-op when N % NB == 0
        float4 pb = pred_boxes[n];
        pcx[i] = pb.x; pcy[i] = pb.y; pw_[i] = pb.z; ph_[i] = pb.w;
        px1[i] = pb.x - 0.5f * pb.z;  py1[i] = pb.y - 0.5f * pb.w;
        px2[i] = pb.x + 0.5f * pb.z;  py2[i] = pb.y + 0.5f * pb.w;
        parea[i] = pb.z * pb.w;
        op[i] = out + (size_t)n * T;
    }
    __syncthreads();

    // ---- phase 2: rotated (load-before-store) target sweep ----
    float4 tb = tgt_boxes[min(tid, T - 1)];              // prologue load
    int    id = tgt_ids[min(tid, T - 1)];

    for (int t = tid; t < T; t += 256) {
        // prefetch NEXT target BEFORE this iteration's stores are issued
        const int tn = min(t + 256, T - 1);
        float4 tb_n = tgt_boxes[tn];
        int    id_n = tgt_ids[tn];

        // class gathers (LDS, lgkmcnt path — independent of stores)
        float clsv[NB] = {fcls[0][id], fcls[1][id], fcls[2][id], fcls[3][id]};

        float tx1 = tb.x - 0.5f * tb.z, ty1 = tb.y - 0.5f * tb.w;
        float tx2 = tb.x + 0.5f * tb.z, ty2 = tb.y + 0.5f * tb.w;
        float tarea = tb.z * tb.w;

#pragma unroll
        for (int i = 0; i < NB; ++i) {
            float l1 = (fabsf(pcx[i] - tb.x) + fabsf(pcy[i] - tb.y))
                     + (fabsf(pw_[i] - tb.z) + fabsf(ph_[i] - tb.w));

            float ix1 = fmaxf(px1[i], tx1), iy1 = fmaxf(py1[i], ty1);
            float ix2 = fminf(px2[i], tx2), iy2 = fminf(py2[i], ty2);
            float iw = fmaxf(ix2 - ix1, 0.0f), ih = fmaxf(iy2 - iy1, 0.0f);
            float inter = iw * ih;
            float uni = parea[i] + tarea - inter;

            float ex1 = fminf(px1[i], tx1), ey1 = fminf(py1[i], ty1);
            float ex2 = fmaxf(px2[i], tx2), ey2 = fmaxf(py2[i], ty2);
            float earea = (ex2 - ex1) * (ey2 - ey1);     // wh >= 0 for [0,1) boxes

            float v = fmaf(5.0f, l1, clsv[i]);           // 5*l1 + 2*cls + 2
            v = fmaf(-2.0f, inter * __builtin_amdgcn_rcpf(uni), v);
            v = fmaf(-2.0f, uni * __builtin_amdgcn_rcpf(earea), v);
            op[i][t] = v;                                // coalesced dword store
        }

        tb = tb_n; id = id_n;                            // rotate
    }
}

extern "C" void kernel_launch(void* const* d_in, const int* in_sizes, int n_in,
                              void* d_out, int out_size, void* d_ws, size_t ws_size,
                              hipStream_t stream) {
    const float* logits = (const float*)d_in[0];   // [bs, Q, C]
    const float* pboxes = (const float*)d_in[1];   // [bs, Q, 4]
    const float* tboxes = (const float*)d_in[2];   // [T, 4]
    const int*   tids   = (const int*)d_in[3];     // [T]

    int N = in_sizes[1] / 4;          // bs*Q = 14400
    int C = in_sizes[0] / N;          // 91
    int T = in_sizes[2] / 4;          // 1600

    int grid = (N + NB - 1) / NB;     // 3600
    fused_cost_kernel<<<grid, 256, 0, stream>>>(
        logits, (const float4*)pboxes, (const float4*)tboxes, tids,
        (float*)d_out, N, C, T);
}